// Round 7
// baseline (314.297 us; speedup 1.0000x reference)
//
#include <hip/hip_runtime.h>
#include <hip/hip_bf16.h>
#include <math.h>

// Problem constants (match reference)
#define B_  4096
#define D_  1024
#define H_  2048
#define C_  1000
#define T_  819200
#define F_  32
#define NPAD2 1024   // W2 rows padded 1000 -> 1024 (row 1000 = Ws, scalar head fused)
#define NPART 1024   // loss partial blocks (B_/4)

typedef __attribute__((ext_vector_type(8))) short short8;
typedef __attribute__((ext_vector_type(4))) float f32x4;

// ---------------- workspace layout (bytes) ----------------
// MFMA operands live in "octet-major" layout: element (row, k) of an
// [Mrows x K] matrix is stored at [(k>>3)*Mrows*8 + row*8 + (k&7)].
static const size_t WS_MEANS    = 0;                               // B*F f32 = 512K
static const size_t WS_PV       = WS_MEANS + (size_t)B_ * F_ * 4;  // NPART f32
static const size_t WS_PA       = WS_PV + NPART * 4;
static const size_t WS_PS       = WS_PA + NPART * 4;
static const size_t WS_B2P      = WS_PS + NPART * 4;               // NPAD2 f32 padded bias
static const size_t WS_COMBINED = 1u << 20;                        // B*D bf16 oct = 8 MiB
static const size_t WS_W1BF     = WS_COMBINED + (size_t)B_ * D_ * 2;   // 4 MiB oct
static const size_t WS_W2BF     = WS_W1BF + (size_t)H_ * D_ * 2;       // 4 MiB oct
static const size_t WS_HIDDEN   = WS_W2BF + (size_t)NPAD2 * H_ * 2;    // B*H bf16 oct = 16 MiB
static const size_t WS_LOGITS   = WS_HIDDEN + (size_t)B_ * H_ * 2;     // B*NPAD2 f32 = 16 MiB

// -------- segment mean: one block per segment, dense coalesced sum --------
// seg_ids sorted => segment b is rows [lower_bound(b), lower_bound(b+1)).
// 2 threads binary-search the bounds; block streams 4 KB/iter; no atomics.
// Writes MEANS directly (division fused; empty segment -> 0, matching ref).
__global__ __launch_bounds__(256) void seg_mean_kernel(
    const float* __restrict__ var_flat, const int* __restrict__ seg_ids,
    float* __restrict__ means) {
  const int seg = blockIdx.x;
  const int tid = threadIdx.x;
  __shared__ int bounds[2];
  if (tid < 2) {
    int tgt = seg + tid;
    int lo = 0, hi = T_;
    while (lo < hi) {               // lower_bound(tgt)
      int mid = (lo + hi) >> 1;
      if (seg_ids[mid] < tgt) lo = mid + 1; else hi = mid;
    }
    bounds[tid] = lo;
  }
  __syncthreads();
  const int start = bounds[0], end = bounds[1];
  const int cnt = end - start;
  const int c4 = (tid & 7) * 4;
  const int rl = tid >> 3;          // 0..31
  float a0 = 0.f, a1 = 0.f, a2 = 0.f, a3 = 0.f;
  for (int r = start + rl; r < end; r += 32) {
    float4 v = *(const float4*)(var_flat + (size_t)r * F_ + c4);
    a0 += v.x; a1 += v.y; a2 += v.z; a3 += v.w;
  }
  // reduce over the 8 row-lanes within each wave (lane stride 8)
#pragma unroll
  for (int o = 8; o < 64; o <<= 1) {
    a0 += __shfl_down(a0, o, 64);
    a1 += __shfl_down(a1, o, 64);
    a2 += __shfl_down(a2, o, 64);
    a3 += __shfl_down(a3, o, 64);
  }
  __shared__ float red[4][8][4];
  const int w = tid >> 6, lane = tid & 63;
  if (lane < 8) {
    red[w][lane][0] = a0; red[w][lane][1] = a1;
    red[w][lane][2] = a2; red[w][lane][3] = a3;
  }
  __syncthreads();
  if (tid < 32) {
    int cg = tid >> 2, e = tid & 3;
    float s = red[0][cg][e] + red[1][cg][e] + red[2][cg][e] + red[3][cg][e];
    float inv = cnt > 0 ? 1.f / (float)cnt : 0.f;
    means[(size_t)seg * F_ + cg * 4 + e] = s * inv;
  }
}

// ---------------- W1 -> octet-major bf16 [D/8][H][8] ----------------
__global__ __launch_bounds__(256) void cvt_w1_oct_kernel(
    const float* __restrict__ W1, __hip_bfloat16* __restrict__ dst) {
  int tid = threadIdx.x;
  int d0 = blockIdx.x * 64;
  int n0 = blockIdx.y * 32;
  int n_l = tid >> 3, kc = tid & 7;
  int n = n0 + n_l;
  int dd = d0 + kc * 8;
  float4 a = *(const float4*)(W1 + (size_t)n * D_ + dd);
  float4 b = *(const float4*)(W1 + (size_t)n * D_ + dd + 4);
  __hip_bfloat16 t[8];
  t[0] = __float2bfloat16(a.x); t[1] = __float2bfloat16(a.y);
  t[2] = __float2bfloat16(a.z); t[3] = __float2bfloat16(a.w);
  t[4] = __float2bfloat16(b.x); t[5] = __float2bfloat16(b.y);
  t[6] = __float2bfloat16(b.z); t[7] = __float2bfloat16(b.w);
  *(uint4*)(dst + ((size_t)(blockIdx.x * 8 + kc) * H_ + n) * 8) = *(uint4*)t;
}

// ---------------- W2+Ws -> octet-major bf16 [H/8][NPAD2][8] ----------------
__global__ __launch_bounds__(256) void cvt_w2_oct_kernel(
    const float* __restrict__ W2, const float* __restrict__ Ws,
    __hip_bfloat16* __restrict__ dst) {
  int tid = threadIdx.x;
  int h0 = blockIdx.x * 64;
  int n0 = blockIdx.y * 32;
  int n_l = tid >> 3, kc = tid & 7;
  int n = n0 + n_l;
  int hh = h0 + kc * 8;
  float va[8] = {0.f, 0.f, 0.f, 0.f, 0.f, 0.f, 0.f, 0.f};
  const float* src = nullptr;
  if (n < C_)       src = W2 + (size_t)n * H_ + hh;
  else if (n == C_) src = Ws + hh;
  if (src) {
    float4 a = *(const float4*)(src);
    float4 b = *(const float4*)(src + 4);
    va[0] = a.x; va[1] = a.y; va[2] = a.z; va[3] = a.w;
    va[4] = b.x; va[5] = b.y; va[6] = b.z; va[7] = b.w;
  }
  __hip_bfloat16 t[8];
#pragma unroll
  for (int e = 0; e < 8; ++e) t[e] = __float2bfloat16(va[e]);
  *(uint4*)(dst + ((size_t)(blockIdx.x * 8 + kc) * NPAD2 + n) * 8) = *(uint4*)t;
}

// padded bias: b2p[0..999]=b2, [1000]=bs, rest 0
__global__ __launch_bounds__(256) void pad_bias_kernel(
    const float* __restrict__ b2, const float* __restrict__ bs,
    float* __restrict__ b2p) {
  int i = blockIdx.x * 256 + threadIdx.x;
  float v = 0.f;
  if (i < C_) v = b2[i];
  else if (i == C_) v = bs[0];
  b2p[i] = v;
}

// ------- combined = feature + means @ Wv^T + bv, octet-major bf16 out -----
__global__ __launch_bounds__(256) void combined_kernel(
    const float* __restrict__ feat, const float* __restrict__ means,
    const float* __restrict__ Wv, const float* __restrict__ bv,
    __hip_bfloat16* __restrict__ comb_oct) {
  __shared__ float m_s[32][F_ + 1];
  __shared__ float wv_s[64][F_ + 1];
  int tid = threadIdx.x;
  int d0 = blockIdx.x * 64;
  int b0 = blockIdx.y * 32;
  {  // stage means (32 x 32)
    int b_l = tid >> 3, f4 = (tid & 7) * 4;
    float4 s4 = *(const float4*)(means + (size_t)(b0 + b_l) * F_ + f4);
    m_s[b_l][f4 + 0] = s4.x; m_s[b_l][f4 + 1] = s4.y;
    m_s[b_l][f4 + 2] = s4.z; m_s[b_l][f4 + 3] = s4.w;
  }
  {  // stage Wv tile (64 x 32)
    int r = tid >> 2, p = (tid & 3) * 8;
    float4 a = *(const float4*)(Wv + (size_t)(d0 + r) * F_ + p);
    float4 b = *(const float4*)(Wv + (size_t)(d0 + r) * F_ + p + 4);
    wv_s[r][p + 0] = a.x; wv_s[r][p + 1] = a.y; wv_s[r][p + 2] = a.z; wv_s[r][p + 3] = a.w;
    wv_s[r][p + 4] = b.x; wv_s[r][p + 5] = b.y; wv_s[r][p + 6] = b.z; wv_s[r][p + 7] = b.w;
  }
  __syncthreads();
  int b_l = tid >> 3, kc = tid & 7;
  int b = b0 + b_l;
  int dbase = d0 + kc * 8;
  float4 f0 = *(const float4*)(feat + (size_t)b * D_ + dbase);
  float4 f1 = *(const float4*)(feat + (size_t)b * D_ + dbase + 4);
  float4 v0 = *(const float4*)(bv + dbase);
  float4 v1 = *(const float4*)(bv + dbase + 4);
  float fv[8]  = {f0.x, f0.y, f0.z, f0.w, f1.x, f1.y, f1.z, f1.w};
  float bvv[8] = {v0.x, v0.y, v0.z, v0.w, v1.x, v1.y, v1.z, v1.w};
  __hip_bfloat16 outv[8];
#pragma unroll
  for (int e = 0; e < 8; ++e) {
    float acc = fv[e] + bvv[e];
    const float* wr = wv_s[kc * 8 + e];
#pragma unroll
    for (int f = 0; f < F_; ++f) acc = fmaf(m_s[b_l][f], wr[f], acc);
    outv[e] = __float2bfloat16(acc);
  }
  *(uint4*)(comb_oct + ((size_t)(blockIdx.x * 8 + kc) * B_ + b) * 8) = *(uint4*)outv;
}

// ------ MFMA bf16 GEMM, octet-major, 4-slab deep-prefetch pipeline --------
// C = A @ B^T + bias. BM=64, BN=128, BK=32 (4 octets), 256 thr (4 waves).
// Slab t+3 is staged right after the barrier for slab t; each wave waits only
// for its OWN 3 oldest loads (vmcnt(6)) before a raw s_barrier, so 6 loads
// stay in flight across every barrier (AITER-style; m97's vmcnt(0) drain
// was the MfmaUtil=10% stall). Buffer reuse safe: slab t+3 overwrites
// buf[(t-1)&3], fully consumed by all waves before barrier t.
__device__ inline void load16_lds(const short* g, short* l) {
  __builtin_amdgcn_global_load_lds(
      (const __attribute__((address_space(1))) void*)g,
      (__attribute__((address_space(3))) void*)l, 16, 0, 0);
}

template <int MODE>  // 0: relu, bf16 octet-major out [Nout/8][M][8]; 1: f32 row-major out
__global__ __launch_bounds__(256) void gemm_mfma_kernel(
    const short* __restrict__ A, const short* __restrict__ Bm,
    const float* __restrict__ bias, void* __restrict__ Cout,
    int M, int Nrows, int K, int Nout) {
  __shared__ short As[4][2048];  // 4 slabs x (4 kc x 64 rows x 8)
  __shared__ short Bs[4][4096];  // 4 slabs x (4 kc x 128 rows x 8)
  const int tid  = threadIdx.x;
  const int lane = tid & 63;
  const int w    = tid >> 6;
  const int bm = blockIdx.y * 64;
  const int bn = blockIdx.x * 128;
  const int wm = (w >> 1) * 32;
  const int wn = (w & 1) * 64;
  const int m_lane = lane & 15;
  const int quad   = lane >> 4;

  f32x4 acc[2][4];
#pragma unroll
  for (int i = 0; i < 2; ++i)
#pragma unroll
    for (int j = 0; j < 4; ++j) acc[i][j] = f32x4{0.f, 0.f, 0.f, 0.f};

  const size_t strideA = (size_t)M * 32;       // elements per 4-octet K-step
  const size_t strideB = (size_t)Nrows * 32;
  const short* pA  = A  + ((size_t)w * M + bm) * 8 + lane * 8;
  const short* pB0 = Bm + ((size_t)w * Nrows + bn) * 8 + lane * 8;
  const short* pB1 = pB0 + 64 * 8;
  const int lA  = w * 512;       // wave-uniform LDS bases (shorts)
  const int lB0 = w * 1024;
  const int lB1 = lB0 + 512;

  // prologue: stage slabs 0,1,2 (K >= 96 always here)
#pragma unroll
  for (int s = 0; s < 3; ++s) {
    load16_lds(pA,  &As[s][lA]);
    load16_lds(pB0, &Bs[s][lB0]);
    load16_lds(pB1, &Bs[s][lB1]);
    pA += strideA; pB0 += strideB; pB1 += strideB;
  }

  const int iters = K >> 5;
  for (int it = 0; it < iters; ++it) {
    // drain only this slab's 3 loads (3 per in-flight slab, newest stay live)
    if (it < iters - 2)       asm volatile("s_waitcnt vmcnt(6)" ::: "memory");
    else if (it == iters - 2) asm volatile("s_waitcnt vmcnt(3)" ::: "memory");
    else                      asm volatile("s_waitcnt vmcnt(0)" ::: "memory");
    asm volatile("s_barrier" ::: "memory");
    if (it + 3 < iters) {
      const int nb = (it + 3) & 3;
      load16_lds(pA,  &As[nb][lA]);
      load16_lds(pB0, &Bs[nb][lB0]);
      load16_lds(pB1, &Bs[nb][lB1]);
      pA += strideA; pB0 += strideB; pB1 += strideB;
    }
    const int cur = it & 3;
    short8 af[2], bf[4];
#pragma unroll
    for (int i = 0; i < 2; ++i)
      af[i] = *(const short8*)&As[cur][quad * 512 + (wm + i * 16 + m_lane) * 8];
#pragma unroll
    for (int j = 0; j < 4; ++j)
      bf[j] = *(const short8*)&Bs[cur][quad * 1024 + (wn + j * 16 + m_lane) * 8];
#pragma unroll
    for (int i = 0; i < 2; ++i)
#pragma unroll
      for (int j = 0; j < 4; ++j)
        acc[i][j] = __builtin_amdgcn_mfma_f32_16x16x32_bf16(af[i], bf[j], acc[i][j], 0, 0, 0);
  }

  // epilogue: C/D layout col=lane&15, row=quad*4+reg
  const int row0 = bm + wm + quad * 4;
  const int col0 = bn + wn + m_lane;
  if (MODE == 0) {
    __hip_bfloat16* Cb = (__hip_bfloat16*)Cout;
#pragma unroll
    for (int j = 0; j < 4; ++j) {
      int col = col0 + j * 16;
      float bsv = bias[col];
      __hip_bfloat16* base = Cb + ((size_t)(col >> 3) * M) * 8 + (col & 7);
#pragma unroll
      for (int i = 0; i < 2; ++i)
#pragma unroll
        for (int r = 0; r < 4; ++r) {
          int row = row0 + i * 16 + r;
          float v = acc[i][j][r] + bsv;
          v = v > 0.f ? v : 0.f;
          base[(size_t)row * 8] = __float2bfloat16(v);
        }
    }
  } else {
    float* Cf = (float*)Cout;
#pragma unroll
    for (int j = 0; j < 4; ++j) {
      int col = col0 + j * 16;
      float bsv = bias[col];
#pragma unroll
      for (int i = 0; i < 2; ++i)
#pragma unroll
        for (int r = 0; r < 4; ++r) {
          int row = row0 + i * 16 + r;
          Cf[(size_t)row * Nout + col] = acc[i][j][r] + bsv;
        }
    }
  }
}

// ------- fused loss: softmax CE + accuracy + scalar MSE (col 1000) --------
__global__ __launch_bounds__(256) void loss_kernel(
    const float* __restrict__ logits, const int* __restrict__ target,
    const float* __restrict__ tgt_scal,
    float* __restrict__ pv, float* __restrict__ pa, float* __restrict__ ps) {
  int tid  = threadIdx.x;
  int lane = tid & 63;
  int w    = tid >> 6;
  int b    = blockIdx.x * 4 + w;
  const float*  row  = logits + (size_t)b * NPAD2;
  const float4* row4 = (const float4*)row;
  float v[16];
  float vmax = -INFINITY;
  int   imax = 0x7fffffff;
#pragma unroll
  for (int k = 0; k < 4; ++k) {
    int c4 = lane + 64 * k;
    float4 x = row4[c4];
    float e0 = x.x, e1 = x.y, e2 = x.z, e3 = x.w;
    int idx = c4 * 4;
    if (idx + 0 >= C_) e0 = -INFINITY;
    if (idx + 1 >= C_) e1 = -INFINITY;
    if (idx + 2 >= C_) e2 = -INFINITY;
    if (idx + 3 >= C_) e3 = -INFINITY;
    v[k * 4 + 0] = e0; v[k * 4 + 1] = e1; v[k * 4 + 2] = e2; v[k * 4 + 3] = e3;
    if (e0 > vmax) { vmax = e0; imax = idx + 0; }
    if (e1 > vmax) { vmax = e1; imax = idx + 1; }
    if (e2 > vmax) { vmax = e2; imax = idx + 2; }
    if (e3 > vmax) { vmax = e3; imax = idx + 3; }
  }
#pragma unroll
  for (int o = 32; o > 0; o >>= 1) {
    float ov = __shfl_down(vmax, o, 64);
    int   oi = __shfl_down(imax, o, 64);
    if (ov > vmax || (ov == vmax && oi < imax)) { vmax = ov; imax = oi; }
  }
  vmax = __shfl(vmax, 0, 64);
  float se = 0.f;
#pragma unroll
  for (int j = 0; j < 16; ++j) se += expf(v[j] - vmax);
#pragma unroll
  for (int o = 32; o > 0; o >>= 1) se += __shfl_down(se, o, 64);
  __shared__ float s_nll[4], s_acc[4], s_sq[4];
  if (lane == 0) {
    int t = target[b];
    float logp = row[t] - vmax - logf(se);
    s_nll[w] = -logp;
    s_acc[w] = (imax == t) ? 1.f : 0.f;
    float d = row[C_] - tgt_scal[b];     // fused scalar head output
    s_sq[w] = d * d;
  }
  __syncthreads();
  if (tid == 0) {
    pv[blockIdx.x] = s_nll[0] + s_nll[1] + s_nll[2] + s_nll[3];
    pa[blockIdx.x] = s_acc[0] + s_acc[1] + s_acc[2] + s_acc[3];
    ps[blockIdx.x] = s_sq[0] + s_sq[1] + s_sq[2] + s_sq[3];
  }
}

// ---------------- finalize: reduce partials ----------------
__global__ __launch_bounds__(256) void finalize_kernel(
    const float* __restrict__ pv, const float* __restrict__ pa,
    const float* __restrict__ ps, float* __restrict__ out) {
  int tid  = threadIdx.x;
  int lane = tid & 63;
  int w    = tid >> 6;
  float nll = 0.f, acc = 0.f, sq = 0.f;
  for (int i = tid; i < NPART; i += 256) {
    nll += pv[i]; acc += pa[i]; sq += ps[i];
  }
#pragma unroll
  for (int o = 32; o > 0; o >>= 1) {
    nll += __shfl_down(nll, o, 64);
    acc += __shfl_down(acc, o, 64);
    sq  += __shfl_down(sq,  o, 64);
  }
  __shared__ float sn[4], sa[4], ss[4];
  if (lane == 0) { sn[w] = nll; sa[w] = acc; ss[w] = sq; }
  __syncthreads();
  if (tid == 0) {
    float lv = (sn[0] + sn[1] + sn[2] + sn[3]) * (1.f / B_);
    float ls = (ss[0] + ss[1] + ss[2] + ss[3]) * (1.f / B_);
    float ac = (sa[0] + sa[1] + sa[2] + sa[3]) * (1.f / B_);
    out[0] = lv + ls;
    out[1] = lv;
    out[2] = ls;
    out[3] = ac;
  }
}

extern "C" void kernel_launch(void* const* d_in, const int* in_sizes, int n_in,
                              void* d_out, int out_size, void* d_ws, size_t ws_size,
                              hipStream_t stream) {
  const float* feature  = (const float*)d_in[0];
  const float* var_flat = (const float*)d_in[1];
  const int*   seg_ids  = (const int*)d_in[2];
  const int*   tgt_vec  = (const int*)d_in[3];
  const float* tgt_scal = (const float*)d_in[4];
  const float* Wv = (const float*)d_in[5];
  const float* bv = (const float*)d_in[6];
  const float* W1 = (const float*)d_in[7];
  const float* b1 = (const float*)d_in[8];
  const float* W2 = (const float*)d_in[9];
  const float* b2 = (const float*)d_in[10];
  const float* Ws = (const float*)d_in[11];
  const float* bs = (const float*)d_in[12];
  float* out = (float*)d_out;

  char* ws = (char*)d_ws;
  float* means  = (float*)(ws + WS_MEANS);
  float* pv     = (float*)(ws + WS_PV);
  float* pa     = (float*)(ws + WS_PA);
  float* ps     = (float*)(ws + WS_PS);
  float* b2p    = (float*)(ws + WS_B2P);
  __hip_bfloat16* comb_oct = (__hip_bfloat16*)(ws + WS_COMBINED);
  __hip_bfloat16* W1oct    = (__hip_bfloat16*)(ws + WS_W1BF);
  __hip_bfloat16* W2oct    = (__hip_bfloat16*)(ws + WS_W2BF);
  __hip_bfloat16* hid_oct  = (__hip_bfloat16*)(ws + WS_HIDDEN);
  float*          logits   = (float*)(ws + WS_LOGITS);

  // 1) segment means (binary-search bounds, dense coalesced sum, no atomics)
  seg_mean_kernel<<<B_, 256, 0, stream>>>(var_flat, seg_ids, means);

  // 2) weight conversions -> octet-major bf16 (+ scalar-head fusion)
  {
    dim3 g1(D_ / 64, H_ / 32);
    cvt_w1_oct_kernel<<<g1, 256, 0, stream>>>(W1, W1oct);
    dim3 g2(H_ / 64, NPAD2 / 32);
    cvt_w2_oct_kernel<<<g2, 256, 0, stream>>>(W2, Ws, W2oct);
    pad_bias_kernel<<<NPAD2 / 256, 256, 0, stream>>>(b2, bs, b2p);
  }

  // 3) combined = feature + means @ Wv^T + bv  (octet-major bf16)
  {
    dim3 grid(D_ / 64, B_ / 32);
    combined_kernel<<<grid, 256, 0, stream>>>(feature, means, Wv, bv, comb_oct);
  }

  // 4) hidden = relu(combined @ W1^T + b1), octet-major out
  {
    dim3 grid(H_ / 128, B_ / 64);     // 16 x 64 = 1024 blocks
    gemm_mfma_kernel<0><<<grid, 256, 0, stream>>>(
        (const short*)comb_oct, (const short*)W1oct, b1, hid_oct, B_, H_, D_, H_);
  }

  // 5) logits[4096 x 1024] = hidden @ W2p^T + b2p (col 1000 = scalar head)
  {
    dim3 grid(NPAD2 / 128, B_ / 64);  // 8 x 64 = 512 blocks
    gemm_mfma_kernel<1><<<grid, 256, 0, stream>>>(
        (const short*)hid_oct, (const short*)W2oct, b2p, logits, B_, NPAD2, H_, NPAD2);
  }

  // 6) fused CE + accuracy + scalar MSE (partials)
  loss_kernel<<<B_ / 4, 256, 0, stream>>>(logits, tgt_vec, tgt_scal, pv, pa, ps);

  // 7) finalize
  finalize_kernel<<<1, 256, 0, stream>>>(pv, pa, ps, out);
}

// Round 8
// 295.395 us; speedup vs baseline: 1.0640x; 1.0640x over previous
//
#include <hip/hip_runtime.h>
#include <hip/hip_bf16.h>
#include <math.h>

// Problem constants (match reference)
#define B_  4096
#define D_  1024
#define H_  2048
#define C_  1000
#define T_  819200
#define F_  32
#define NPAD2 1024   // W2 rows padded 1000 -> 1024 (row 1000 = Ws, scalar head fused)
#define NPART 1024   // loss partial blocks (B_/4)

typedef __attribute__((ext_vector_type(8))) short short8;
typedef __attribute__((ext_vector_type(4))) float f32x4;

// ---------------- workspace layout (bytes) ----------------
// MFMA operands live in "octet-major" layout: element (row, k) of an
// [Mrows x K] matrix is stored at [(k>>3)*Mrows*8 + row*8 + (k&7)].
static const size_t WS_MEANS    = 0;                               // B*F f32 = 512K
static const size_t WS_PV       = WS_MEANS + (size_t)B_ * F_ * 4;  // NPART f32
static const size_t WS_PA       = WS_PV + NPART * 4;
static const size_t WS_PS       = WS_PA + NPART * 4;
static const size_t WS_B2P      = WS_PS + NPART * 4;               // NPAD2 f32 padded bias
static const size_t WS_COMBINED = 1u << 20;                        // B*D bf16 oct = 8 MiB
static const size_t WS_W1BF     = WS_COMBINED + (size_t)B_ * D_ * 2;   // 4 MiB oct
static const size_t WS_W2BF     = WS_W1BF + (size_t)H_ * D_ * 2;       // 4 MiB oct
static const size_t WS_HIDDEN   = WS_W2BF + (size_t)NPAD2 * H_ * 2;    // B*H bf16 oct = 16 MiB
static const size_t WS_LOGITS   = WS_HIDDEN + (size_t)B_ * H_ * 2;     // B*NPAD2 f32 = 16 MiB

// ---------------- merged prep: seg_mean | cvt_w1 | cvt_w2 | pad_bias ------
// All four jobs are independent; one dispatch lets the BW-bound segment sum
// overlap the latency-bound weight converts, and kills 3 dispatch gaps.
// Block id decode: [0,4096) seg_mean, [4096,5120) cvt_w1, [5120,6144) cvt_w2,
// [6144,6148) pad_bias.
#define PREP_BLOCKS (B_ + 1024 + 1024 + 4)
__global__ __launch_bounds__(256) void prep_kernel(
    const float* __restrict__ var_flat, const int* __restrict__ seg_ids,
    float* __restrict__ means,
    const float* __restrict__ W1, __hip_bfloat16* __restrict__ W1oct,
    const float* __restrict__ W2, const float* __restrict__ Wsc,
    __hip_bfloat16* __restrict__ W2oct,
    const float* __restrict__ b2, const float* __restrict__ bsc,
    float* __restrict__ b2p) {
  const int id  = blockIdx.x;
  const int tid = threadIdx.x;

  if (id < B_) {
    // ---- segment mean: sorted ids => segment = contiguous row range ----
    const int seg = id;
    __shared__ int bounds[2];
    __shared__ float red[4][8][4];
    if (tid < 2) {
      int tgt = seg + tid;
      int lo = 0, hi = T_;
      while (lo < hi) {             // lower_bound(tgt)
        int mid = (lo + hi) >> 1;
        if (seg_ids[mid] < tgt) lo = mid + 1; else hi = mid;
      }
      bounds[tid] = lo;
    }
    __syncthreads();
    const int start = bounds[0], end = bounds[1];
    const int cnt = end - start;
    const int c4 = (tid & 7) * 4;
    const int rl = tid >> 3;        // 0..31
    float a0 = 0.f, a1 = 0.f, a2 = 0.f, a3 = 0.f;
    for (int r = start + rl; r < end; r += 32) {
      float4 v = *(const float4*)(var_flat + (size_t)r * F_ + c4);
      a0 += v.x; a1 += v.y; a2 += v.z; a3 += v.w;
    }
#pragma unroll
    for (int o = 8; o < 64; o <<= 1) {
      a0 += __shfl_down(a0, o, 64);
      a1 += __shfl_down(a1, o, 64);
      a2 += __shfl_down(a2, o, 64);
      a3 += __shfl_down(a3, o, 64);
    }
    const int w = tid >> 6, lane = tid & 63;
    if (lane < 8) {
      red[w][lane][0] = a0; red[w][lane][1] = a1;
      red[w][lane][2] = a2; red[w][lane][3] = a3;
    }
    __syncthreads();
    if (tid < 32) {
      int cg = tid >> 2, e = tid & 3;
      float s = red[0][cg][e] + red[1][cg][e] + red[2][cg][e] + red[3][cg][e];
      float inv = cnt > 0 ? 1.f / (float)cnt : 0.f;
      means[(size_t)seg * F_ + cg * 4 + e] = s * inv;
    }
    return;
  }

  if (id < B_ + 1024) {
    // ---- W1 -> octet-major bf16 [D/8][H][8]; grid was (16 d-tiles, 64 n-tiles)
    int t = id - B_;
    int bx = t & 15, by = t >> 4;
    int d0 = bx * 64, n0 = by * 32;
    int n_l = tid >> 3, kc = tid & 7;
    int n = n0 + n_l;
    int dd = d0 + kc * 8;
    float4 a = *(const float4*)(W1 + (size_t)n * D_ + dd);
    float4 b = *(const float4*)(W1 + (size_t)n * D_ + dd + 4);
    __hip_bfloat16 tb[8];
    tb[0] = __float2bfloat16(a.x); tb[1] = __float2bfloat16(a.y);
    tb[2] = __float2bfloat16(a.z); tb[3] = __float2bfloat16(a.w);
    tb[4] = __float2bfloat16(b.x); tb[5] = __float2bfloat16(b.y);
    tb[6] = __float2bfloat16(b.z); tb[7] = __float2bfloat16(b.w);
    *(uint4*)(W1oct + ((size_t)(bx * 8 + kc) * H_ + n) * 8) = *(uint4*)tb;
    return;
  }

  if (id < B_ + 2048) {
    // ---- W2+Ws -> octet-major bf16 [H/8][NPAD2][8]; grid was (32, 32) ----
    int t = id - B_ - 1024;
    int bx = t & 31, by = t >> 5;
    int h0 = bx * 64, n0 = by * 32;
    int n_l = tid >> 3, kc = tid & 7;
    int n = n0 + n_l;
    int hh = h0 + kc * 8;
    float va[8] = {0.f, 0.f, 0.f, 0.f, 0.f, 0.f, 0.f, 0.f};
    const float* src = nullptr;
    if (n < C_)       src = W2 + (size_t)n * H_ + hh;
    else if (n == C_) src = Wsc + hh;
    if (src) {
      float4 a = *(const float4*)(src);
      float4 b = *(const float4*)(src + 4);
      va[0] = a.x; va[1] = a.y; va[2] = a.z; va[3] = a.w;
      va[4] = b.x; va[5] = b.y; va[6] = b.z; va[7] = b.w;
    }
    __hip_bfloat16 tb[8];
#pragma unroll
    for (int e = 0; e < 8; ++e) tb[e] = __float2bfloat16(va[e]);
    *(uint4*)(W2oct + ((size_t)(bx * 8 + kc) * NPAD2 + n) * 8) = *(uint4*)tb;
    return;
  }

  // ---- padded bias: b2p[0..999]=b2, [1000]=bs, rest 0 ----
  {
    int i = (id - B_ - 2048) * 256 + tid;
    float v = 0.f;
    if (i < C_) v = b2[i];
    else if (i == C_) v = bsc[0];
    b2p[i] = v;
  }
}

// ------- combined = feature + means @ Wv^T + bv, octet-major bf16 out -----
__global__ __launch_bounds__(256) void combined_kernel(
    const float* __restrict__ feat, const float* __restrict__ means,
    const float* __restrict__ Wv, const float* __restrict__ bv,
    __hip_bfloat16* __restrict__ comb_oct) {
  __shared__ float m_s[32][F_ + 1];
  __shared__ float wv_s[64][F_ + 1];
  int tid = threadIdx.x;
  int d0 = blockIdx.x * 64;
  int b0 = blockIdx.y * 32;
  {  // stage means (32 x 32)
    int b_l = tid >> 3, f4 = (tid & 7) * 4;
    float4 s4 = *(const float4*)(means + (size_t)(b0 + b_l) * F_ + f4);
    m_s[b_l][f4 + 0] = s4.x; m_s[b_l][f4 + 1] = s4.y;
    m_s[b_l][f4 + 2] = s4.z; m_s[b_l][f4 + 3] = s4.w;
  }
  {  // stage Wv tile (64 x 32)
    int r = tid >> 2, p = (tid & 3) * 8;
    float4 a = *(const float4*)(Wv + (size_t)(d0 + r) * F_ + p);
    float4 b = *(const float4*)(Wv + (size_t)(d0 + r) * F_ + p + 4);
    wv_s[r][p + 0] = a.x; wv_s[r][p + 1] = a.y; wv_s[r][p + 2] = a.z; wv_s[r][p + 3] = a.w;
    wv_s[r][p + 4] = b.x; wv_s[r][p + 5] = b.y; wv_s[r][p + 6] = b.z; wv_s[r][p + 7] = b.w;
  }
  __syncthreads();
  int b_l = tid >> 3, kc = tid & 7;
  int b = b0 + b_l;
  int dbase = d0 + kc * 8;
  float4 f0 = *(const float4*)(feat + (size_t)b * D_ + dbase);
  float4 f1 = *(const float4*)(feat + (size_t)b * D_ + dbase + 4);
  float4 v0 = *(const float4*)(bv + dbase);
  float4 v1 = *(const float4*)(bv + dbase + 4);
  float fv[8]  = {f0.x, f0.y, f0.z, f0.w, f1.x, f1.y, f1.z, f1.w};
  float bvv[8] = {v0.x, v0.y, v0.z, v0.w, v1.x, v1.y, v1.z, v1.w};
  __hip_bfloat16 outv[8];
#pragma unroll
  for (int e = 0; e < 8; ++e) {
    float acc = fv[e] + bvv[e];
    const float* wr = wv_s[kc * 8 + e];
#pragma unroll
    for (int f = 0; f < F_; ++f) acc = fmaf(m_s[b_l][f], wr[f], acc);
    outv[e] = __float2bfloat16(acc);
  }
  *(uint4*)(comb_oct + ((size_t)(blockIdx.x * 8 + kc) * B_ + b) * 8) = *(uint4*)outv;
}

// ---------------- MFMA bf16 GEMM, octet-major, double-buffered LDS --------
// C = A @ B^T + bias. BM=64, BN=128, BK=32 (4 octets), 256 thr (4 waves,
// 2x2 wave-tiles of 32x64). Octet-major operands => each staging instruction
// is a fully-coalesced contiguous 1 KB global_load_lds_dwordx4.
// (Round-7 lesson: inline-asm vmcnt pipelines regress — compiler inserts its
// own vmcnt(0) around asm with memory clobbers. __syncthreads dbuf is the
// local optimum for this K-loop shape; see m99/m131-m141.)
__device__ inline void load16_lds(const short* g, short* l) {
  __builtin_amdgcn_global_load_lds(
      (const __attribute__((address_space(1))) void*)g,
      (__attribute__((address_space(3))) void*)l, 16, 0, 0);
}

template <int MODE>  // 0: relu, bf16 octet-major out [Nout/8][M][8]; 1: f32 row-major out
__global__ __launch_bounds__(256) void gemm_mfma_kernel(
    const short* __restrict__ A, const short* __restrict__ Bm,
    const float* __restrict__ bias, void* __restrict__ Cout,
    int M, int Nrows, int K, int Nout) {
  __shared__ short As[2][2048];  // 2 slabs x (4 kc x 64 rows x 8)
  __shared__ short Bs[2][4096];  // 2 slabs x (4 kc x 128 rows x 8)
  const int tid  = threadIdx.x;
  const int lane = tid & 63;
  const int w    = tid >> 6;
  const int bm = blockIdx.y * 64;
  const int bn = blockIdx.x * 128;
  const int wm = (w >> 1) * 32;
  const int wn = (w & 1) * 64;
  const int m_lane = lane & 15;
  const int quad   = lane >> 4;

  f32x4 acc[2][4];
#pragma unroll
  for (int i = 0; i < 2; ++i)
#pragma unroll
    for (int j = 0; j < 4; ++j) acc[i][j] = f32x4{0.f, 0.f, 0.f, 0.f};

  const size_t strideA = (size_t)M * 32;       // elements per 4-octet K-step
  const size_t strideB = (size_t)Nrows * 32;
  const short* pA  = A  + ((size_t)w * M + bm) * 8 + lane * 8;
  const short* pB0 = Bm + ((size_t)w * Nrows + bn) * 8 + lane * 8;
  const short* pB1 = pB0 + 64 * 8;
  const int lA  = w * 512;       // wave-uniform LDS bases (shorts)
  const int lB0 = w * 1024;
  const int lB1 = lB0 + 512;

  // prologue: stage slab 0 into buf 0
  load16_lds(pA,  &As[0][lA]);
  load16_lds(pB0, &Bs[0][lB0]);
  load16_lds(pB1, &Bs[0][lB1]);

  const int iters = K >> 5;
  for (int it = 0; it < iters; ++it) {
    const int cur = it & 1, nxt = cur ^ 1;
    __syncthreads();   // drains buf[cur] staging; guards buf[nxt] reuse
    if (it + 1 < iters) {
      pA += strideA; pB0 += strideB; pB1 += strideB;
      load16_lds(pA,  &As[nxt][lA]);
      load16_lds(pB0, &Bs[nxt][lB0]);
      load16_lds(pB1, &Bs[nxt][lB1]);
    }
    short8 af[2], bf[4];
#pragma unroll
    for (int i = 0; i < 2; ++i)
      af[i] = *(const short8*)&As[cur][quad * 512 + (wm + i * 16 + m_lane) * 8];
#pragma unroll
    for (int j = 0; j < 4; ++j)
      bf[j] = *(const short8*)&Bs[cur][quad * 1024 + (wn + j * 16 + m_lane) * 8];
#pragma unroll
    for (int i = 0; i < 2; ++i)
#pragma unroll
      for (int j = 0; j < 4; ++j)
        acc[i][j] = __builtin_amdgcn_mfma_f32_16x16x32_bf16(af[i], bf[j], acc[i][j], 0, 0, 0);
  }

  // epilogue: C/D layout col=lane&15, row=quad*4+reg
  const int row0 = bm + wm + quad * 4;
  const int col0 = bn + wn + m_lane;
  if (MODE == 0) {
    __hip_bfloat16* Cb = (__hip_bfloat16*)Cout;
#pragma unroll
    for (int j = 0; j < 4; ++j) {
      int col = col0 + j * 16;
      float bsv = bias[col];
      __hip_bfloat16* base = Cb + ((size_t)(col >> 3) * M) * 8 + (col & 7);
#pragma unroll
      for (int i = 0; i < 2; ++i)
#pragma unroll
        for (int r = 0; r < 4; ++r) {
          int row = row0 + i * 16 + r;
          float v = acc[i][j][r] + bsv;
          v = v > 0.f ? v : 0.f;
          base[(size_t)row * 8] = __float2bfloat16(v);
        }
    }
  } else {
    float* Cf = (float*)Cout;
#pragma unroll
    for (int j = 0; j < 4; ++j) {
      int col = col0 + j * 16;
      float bsv = bias[col];
#pragma unroll
      for (int i = 0; i < 2; ++i)
#pragma unroll
        for (int r = 0; r < 4; ++r) {
          int row = row0 + i * 16 + r;
          Cf[(size_t)row * Nout + col] = acc[i][j][r] + bsv;
        }
    }
  }
}

// ------- fused loss: softmax CE + accuracy + scalar MSE (col 1000) --------
__global__ __launch_bounds__(256) void loss_kernel(
    const float* __restrict__ logits, const int* __restrict__ target,
    const float* __restrict__ tgt_scal,
    float* __restrict__ pv, float* __restrict__ pa, float* __restrict__ ps) {
  int tid  = threadIdx.x;
  int lane = tid & 63;
  int w    = tid >> 6;
  int b    = blockIdx.x * 4 + w;
  const float*  row  = logits + (size_t)b * NPAD2;
  const float4* row4 = (const float4*)row;
  float v[16];
  float vmax = -INFINITY;
  int   imax = 0x7fffffff;
#pragma unroll
  for (int k = 0; k < 4; ++k) {
    int c4 = lane + 64 * k;
    float4 x = row4[c4];
    float e0 = x.x, e1 = x.y, e2 = x.z, e3 = x.w;
    int idx = c4 * 4;
    if (idx + 0 >= C_) e0 = -INFINITY;
    if (idx + 1 >= C_) e1 = -INFINITY;
    if (idx + 2 >= C_) e2 = -INFINITY;
    if (idx + 3 >= C_) e3 = -INFINITY;
    v[k * 4 + 0] = e0; v[k * 4 + 1] = e1; v[k * 4 + 2] = e2; v[k * 4 + 3] = e3;
    if (e0 > vmax) { vmax = e0; imax = idx + 0; }
    if (e1 > vmax) { vmax = e1; imax = idx + 1; }
    if (e2 > vmax) { vmax = e2; imax = idx + 2; }
    if (e3 > vmax) { vmax = e3; imax = idx + 3; }
  }
#pragma unroll
  for (int o = 32; o > 0; o >>= 1) {
    float ov = __shfl_down(vmax, o, 64);
    int   oi = __shfl_down(imax, o, 64);
    if (ov > vmax || (ov == vmax && oi < imax)) { vmax = ov; imax = oi; }
  }
  vmax = __shfl(vmax, 0, 64);
  float se = 0.f;
#pragma unroll
  for (int j = 0; j < 16; ++j) se += expf(v[j] - vmax);
#pragma unroll
  for (int o = 32; o > 0; o >>= 1) se += __shfl_down(se, o, 64);
  __shared__ float s_nll[4], s_acc[4], s_sq[4];
  if (lane == 0) {
    int t = target[b];
    float logp = row[t] - vmax - logf(se);
    s_nll[w] = -logp;
    s_acc[w] = (imax == t) ? 1.f : 0.f;
    float d = row[C_] - tgt_scal[b];     // fused scalar head output
    s_sq[w] = d * d;
  }
  __syncthreads();
  if (tid == 0) {
    pv[blockIdx.x] = s_nll[0] + s_nll[1] + s_nll[2] + s_nll[3];
    pa[blockIdx.x] = s_acc[0] + s_acc[1] + s_acc[2] + s_acc[3];
    ps[blockIdx.x] = s_sq[0] + s_sq[1] + s_sq[2] + s_sq[3];
  }
}

// ---------------- finalize: reduce partials ----------------
__global__ __launch_bounds__(256) void finalize_kernel(
    const float* __restrict__ pv, const float* __restrict__ pa,
    const float* __restrict__ ps, float* __restrict__ out) {
  int tid  = threadIdx.x;
  int lane = tid & 63;
  int w    = tid >> 6;
  float nll = 0.f, acc = 0.f, sq = 0.f;
  for (int i = tid; i < NPART; i += 256) {
    nll += pv[i]; acc += pa[i]; sq += ps[i];
  }
#pragma unroll
  for (int o = 32; o > 0; o >>= 1) {
    nll += __shfl_down(nll, o, 64);
    acc += __shfl_down(acc, o, 64);
    sq  += __shfl_down(sq,  o, 64);
  }
  __shared__ float sn[4], sa[4], ss[4];
  if (lane == 0) { sn[w] = nll; sa[w] = acc; ss[w] = sq; }
  __syncthreads();
  if (tid == 0) {
    float lv = (sn[0] + sn[1] + sn[2] + sn[3]) * (1.f / B_);
    float ls = (ss[0] + ss[1] + ss[2] + ss[3]) * (1.f / B_);
    float ac = (sa[0] + sa[1] + sa[2] + sa[3]) * (1.f / B_);
    out[0] = lv + ls;
    out[1] = lv;
    out[2] = ls;
    out[3] = ac;
  }
}

extern "C" void kernel_launch(void* const* d_in, const int* in_sizes, int n_in,
                              void* d_out, int out_size, void* d_ws, size_t ws_size,
                              hipStream_t stream) {
  const float* feature  = (const float*)d_in[0];
  const float* var_flat = (const float*)d_in[1];
  const int*   seg_ids  = (const int*)d_in[2];
  const int*   tgt_vec  = (const int*)d_in[3];
  const float* tgt_scal = (const float*)d_in[4];
  const float* Wv = (const float*)d_in[5];
  const float* bv = (const float*)d_in[6];
  const float* W1 = (const float*)d_in[7];
  const float* b1 = (const float*)d_in[8];
  const float* W2 = (const float*)d_in[9];
  const float* b2 = (const float*)d_in[10];
  const float* Ws = (const float*)d_in[11];
  const float* bs = (const float*)d_in[12];
  float* out = (float*)d_out;

  char* ws = (char*)d_ws;
  float* means  = (float*)(ws + WS_MEANS);
  float* pv     = (float*)(ws + WS_PV);
  float* pa     = (float*)(ws + WS_PA);
  float* ps     = (float*)(ws + WS_PS);
  float* b2p    = (float*)(ws + WS_B2P);
  __hip_bfloat16* comb_oct = (__hip_bfloat16*)(ws + WS_COMBINED);
  __hip_bfloat16* W1oct    = (__hip_bfloat16*)(ws + WS_W1BF);
  __hip_bfloat16* W2oct    = (__hip_bfloat16*)(ws + WS_W2BF);
  __hip_bfloat16* hid_oct  = (__hip_bfloat16*)(ws + WS_HIDDEN);
  float*          logits   = (float*)(ws + WS_LOGITS);

  // 1) merged prep: segment means + weight converts + bias pad (1 dispatch)
  prep_kernel<<<PREP_BLOCKS, 256, 0, stream>>>(
      var_flat, seg_ids, means, W1, W1oct, W2, Ws, W2oct, b2, bs, b2p);

  // 2) combined = feature + means @ Wv^T + bv  (octet-major bf16)
  {
    dim3 grid(D_ / 64, B_ / 32);
    combined_kernel<<<grid, 256, 0, stream>>>(feature, means, Wv, bv, comb_oct);
  }

  // 3) hidden = relu(combined @ W1^T + b1), octet-major out
  {
    dim3 grid(H_ / 128, B_ / 64);     // 16 x 64 = 1024 blocks
    gemm_mfma_kernel<0><<<grid, 256, 0, stream>>>(
        (const short*)comb_oct, (const short*)W1oct, b1, hid_oct, B_, H_, D_, H_);
  }

  // 4) logits[4096 x 1024] = hidden @ W2p^T + b2p (col 1000 = scalar head)
  {
    dim3 grid(NPAD2 / 128, B_ / 64);  // 8 x 64 = 512 blocks
    gemm_mfma_kernel<1><<<grid, 256, 0, stream>>>(
        (const short*)hid_oct, (const short*)W2oct, b2p, logits, B_, NPAD2, H_, NPAD2);
  }

  // 5) fused CE + accuracy + scalar MSE (partials)
  loss_kernel<<<B_ / 4, 256, 0, stream>>>(logits, tgt_vec, tgt_scal, pv, pa, ps);

  // 6) finalize
  finalize_kernel<<<1, 256, 0, stream>>>(pv, pa, ps, out);
}

// Round 9
// 284.446 us; speedup vs baseline: 1.1049x; 1.0385x over previous
//
#include <hip/hip_runtime.h>
#include <hip/hip_bf16.h>
#include <math.h>

// Problem constants (match reference)
#define B_  4096
#define D_  1024
#define H_  2048
#define C_  1000
#define T_  819200
#define F_  32
#define NPAD2 1024   // W2 rows padded 1000 -> 1024 (row 1000 = Ws, scalar head fused)
#define NPART 1024   // loss partial blocks (B_/4)

typedef __attribute__((ext_vector_type(8))) short short8;
typedef __attribute__((ext_vector_type(4))) float f32x4;

// ---------------- workspace layout (bytes) ----------------
// MFMA operands live in "octet-major" layout: element (row, k) of an
// [Mrows x K] matrix is stored at [(k>>3)*Mrows*8 + row*8 + (k&7)].
static const size_t WS_MEANS    = 0;                               // B*F f32 = 512K
static const size_t WS_PV       = WS_MEANS + (size_t)B_ * F_ * 4;  // NPART f32
static const size_t WS_PA       = WS_PV + NPART * 4;
static const size_t WS_PS       = WS_PA + NPART * 4;
static const size_t WS_B2P      = WS_PS + NPART * 4;               // NPAD2 f32 padded bias
static const size_t WS_STARTS   = WS_B2P + NPAD2 * 4;              // (B_+1) int
static const size_t WS_COMBINED = 1u << 20;                        // B*D bf16 oct = 8 MiB
static const size_t WS_W1BF     = WS_COMBINED + (size_t)B_ * D_ * 2;   // 4 MiB oct
static const size_t WS_W2BF     = WS_W1BF + (size_t)H_ * D_ * 2;       // 4 MiB oct
static const size_t WS_HIDDEN   = WS_W2BF + (size_t)NPAD2 * H_ * 2;    // B*H bf16 oct = 16 MiB
static const size_t WS_LOGITS   = WS_HIDDEN + (size_t)B_ * H_ * 2;     // B*NPAD2 f32 = 16 MiB

// ------- boundary pre-pass: starts[s] = lower_bound(seg_ids, s) -----------
// One streaming scan; transitions write their covered range. starts[B_] = T_.
__global__ __launch_bounds__(256) void bounds_kernel(
    const int* __restrict__ seg_ids, int* __restrict__ starts) {
  int i = blockIdx.x * 256 + threadIdx.x;
  if (i >= T_) return;
  int cur  = seg_ids[i];
  int prev = (i == 0) ? -1 : seg_ids[i - 1];
  for (int s = prev + 1; s <= cur; ++s) starts[s] = i;
  if (i == T_ - 1)
    for (int s = cur + 1; s <= B_; ++s) starts[s] = T_;
}

// ---------------- merged prep: cvt_w1 | cvt_w2 | pad_bias | seg_mean ------
// Converts first so the BW-bound seg blocks pack the dispatch tail.
// Block id decode: [0,1024) cvt_w1, [1024,2048) cvt_w2, [2048,2052) pad_bias,
// [2052, 2052+B_) seg_mean.
#define PREP_BLOCKS (1024 + 1024 + 4 + B_)
__global__ __launch_bounds__(256) void prep_kernel(
    const float* __restrict__ var_flat, const int* __restrict__ starts,
    float* __restrict__ means,
    const float* __restrict__ W1, __hip_bfloat16* __restrict__ W1oct,
    const float* __restrict__ W2, const float* __restrict__ Wsc,
    __hip_bfloat16* __restrict__ W2oct,
    const float* __restrict__ b2, const float* __restrict__ bsc,
    float* __restrict__ b2p) {
  const int id  = blockIdx.x;
  const int tid = threadIdx.x;

  if (id < 1024) {
    // ---- W1 -> octet-major bf16 [D/8][H][8] (16 d-tiles x 64 n-tiles) ----
    int bx = id & 15, by = id >> 4;
    int d0 = bx * 64, n0 = by * 32;
    int n_l = tid >> 3, kc = tid & 7;
    int n = n0 + n_l;
    int dd = d0 + kc * 8;
    float4 a = *(const float4*)(W1 + (size_t)n * D_ + dd);
    float4 b = *(const float4*)(W1 + (size_t)n * D_ + dd + 4);
    __hip_bfloat16 tb[8];
    tb[0] = __float2bfloat16(a.x); tb[1] = __float2bfloat16(a.y);
    tb[2] = __float2bfloat16(a.z); tb[3] = __float2bfloat16(a.w);
    tb[4] = __float2bfloat16(b.x); tb[5] = __float2bfloat16(b.y);
    tb[6] = __float2bfloat16(b.z); tb[7] = __float2bfloat16(b.w);
    *(uint4*)(W1oct + ((size_t)(bx * 8 + kc) * H_ + n) * 8) = *(uint4*)tb;
    return;
  }

  if (id < 2048) {
    // ---- W2+Ws -> octet-major bf16 [H/8][NPAD2][8] (32 x 32 tiles) ----
    int t = id - 1024;
    int bx = t & 31, by = t >> 5;
    int h0 = bx * 64, n0 = by * 32;
    int n_l = tid >> 3, kc = tid & 7;
    int n = n0 + n_l;
    int hh = h0 + kc * 8;
    float va[8] = {0.f, 0.f, 0.f, 0.f, 0.f, 0.f, 0.f, 0.f};
    const float* src = nullptr;
    if (n < C_)       src = W2 + (size_t)n * H_ + hh;
    else if (n == C_) src = Wsc + hh;
    if (src) {
      float4 a = *(const float4*)(src);
      float4 b = *(const float4*)(src + 4);
      va[0] = a.x; va[1] = a.y; va[2] = a.z; va[3] = a.w;
      va[4] = b.x; va[5] = b.y; va[6] = b.z; va[7] = b.w;
    }
    __hip_bfloat16 tb[8];
#pragma unroll
    for (int e = 0; e < 8; ++e) tb[e] = __float2bfloat16(va[e]);
    *(uint4*)(W2oct + ((size_t)(bx * 8 + kc) * NPAD2 + n) * 8) = *(uint4*)tb;
    return;
  }

  if (id < 2052) {
    // ---- padded bias: b2p[0..999]=b2, [1000]=bs, rest 0 ----
    int i = (id - 2048) * 256 + tid;
    float v = 0.f;
    if (i < C_) v = b2[i];
    else if (i == C_) v = bsc[0];
    b2p[i] = v;
    return;
  }

  // ---- segment mean: bounds precomputed, dense coalesced 2x-unrolled sum --
  {
    const int seg = id - 2052;
    const int start = starts[seg];        // uniform -> scalar load
    const int end   = starts[seg + 1];
    const int cnt = end - start;
    const int c4 = (tid & 7) * 4;
    const int rl = tid >> 3;              // 0..31
    float a0 = 0.f, a1 = 0.f, a2 = 0.f, a3 = 0.f;
    float b0 = 0.f, b1 = 0.f, b2v = 0.f, b3 = 0.f;
    int r = start + rl;
    for (; r + 32 < end; r += 64) {       // 2 independent loads in flight
      float4 v = *(const float4*)(var_flat + (size_t)r * F_ + c4);
      float4 u = *(const float4*)(var_flat + (size_t)(r + 32) * F_ + c4);
      a0 += v.x; a1 += v.y; a2 += v.z; a3 += v.w;
      b0 += u.x; b1 += u.y; b2v += u.z; b3 += u.w;
    }
    if (r < end) {
      float4 v = *(const float4*)(var_flat + (size_t)r * F_ + c4);
      a0 += v.x; a1 += v.y; a2 += v.z; a3 += v.w;
    }
    a0 += b0; a1 += b1; a2 += b2v; a3 += b3;
#pragma unroll
    for (int o = 8; o < 64; o <<= 1) {
      a0 += __shfl_down(a0, o, 64);
      a1 += __shfl_down(a1, o, 64);
      a2 += __shfl_down(a2, o, 64);
      a3 += __shfl_down(a3, o, 64);
    }
    __shared__ float red[4][8][4];
    const int w = tid >> 6, lane = tid & 63;
    if (lane < 8) {
      red[w][lane][0] = a0; red[w][lane][1] = a1;
      red[w][lane][2] = a2; red[w][lane][3] = a3;
    }
    __syncthreads();
    if (tid < 32) {
      int cg = tid >> 2, e = tid & 3;
      float s = red[0][cg][e] + red[1][cg][e] + red[2][cg][e] + red[3][cg][e];
      float inv = cnt > 0 ? 1.f / (float)cnt : 0.f;
      means[(size_t)seg * F_ + cg * 4 + e] = s * inv;
    }
  }
}

// ------- combined = feature + means @ Wv^T + bv, octet-major bf16 out -----
__global__ __launch_bounds__(256) void combined_kernel(
    const float* __restrict__ feat, const float* __restrict__ means,
    const float* __restrict__ Wv, const float* __restrict__ bv,
    __hip_bfloat16* __restrict__ comb_oct) {
  __shared__ float m_s[32][F_ + 1];
  __shared__ float wv_s[64][F_ + 1];
  int tid = threadIdx.x;
  int d0 = blockIdx.x * 64;
  int b0 = blockIdx.y * 32;
  {  // stage means (32 x 32)
    int b_l = tid >> 3, f4 = (tid & 7) * 4;
    float4 s4 = *(const float4*)(means + (size_t)(b0 + b_l) * F_ + f4);
    m_s[b_l][f4 + 0] = s4.x; m_s[b_l][f4 + 1] = s4.y;
    m_s[b_l][f4 + 2] = s4.z; m_s[b_l][f4 + 3] = s4.w;
  }
  {  // stage Wv tile (64 x 32)
    int r = tid >> 2, p = (tid & 3) * 8;
    float4 a = *(const float4*)(Wv + (size_t)(d0 + r) * F_ + p);
    float4 b = *(const float4*)(Wv + (size_t)(d0 + r) * F_ + p + 4);
    wv_s[r][p + 0] = a.x; wv_s[r][p + 1] = a.y; wv_s[r][p + 2] = a.z; wv_s[r][p + 3] = a.w;
    wv_s[r][p + 4] = b.x; wv_s[r][p + 5] = b.y; wv_s[r][p + 6] = b.z; wv_s[r][p + 7] = b.w;
  }
  __syncthreads();
  int b_l = tid >> 3, kc = tid & 7;
  int b = b0 + b_l;
  int dbase = d0 + kc * 8;
  float4 f0 = *(const float4*)(feat + (size_t)b * D_ + dbase);
  float4 f1 = *(const float4*)(feat + (size_t)b * D_ + dbase + 4);
  float4 v0 = *(const float4*)(bv + dbase);
  float4 v1 = *(const float4*)(bv + dbase + 4);
  float fv[8]  = {f0.x, f0.y, f0.z, f0.w, f1.x, f1.y, f1.z, f1.w};
  float bvv[8] = {v0.x, v0.y, v0.z, v0.w, v1.x, v1.y, v1.z, v1.w};
  __hip_bfloat16 outv[8];
#pragma unroll
  for (int e = 0; e < 8; ++e) {
    float acc = fv[e] + bvv[e];
    const float* wr = wv_s[kc * 8 + e];
#pragma unroll
    for (int f = 0; f < F_; ++f) acc = fmaf(m_s[b_l][f], wr[f], acc);
    outv[e] = __float2bfloat16(acc);
  }
  *(uint4*)(comb_oct + ((size_t)(blockIdx.x * 8 + kc) * B_ + b) * 8) = *(uint4*)outv;
}

// ---------------- MFMA bf16 GEMM, octet-major, double-buffered LDS --------
// C = A @ B^T + bias. BM=64, BN=128, BK=32 (4 octets), 256 thr (4 waves,
// 2x2 wave-tiles of 32x64). Octet-major operands => each staging instruction
// is a fully-coalesced contiguous 1 KB global_load_lds_dwordx4.
__device__ inline void load16_lds(const short* g, short* l) {
  __builtin_amdgcn_global_load_lds(
      (const __attribute__((address_space(1))) void*)g,
      (__attribute__((address_space(3))) void*)l, 16, 0, 0);
}

template <int MODE>  // 0: relu, bf16 octet-major out [Nout/8][M][8]; 1: f32 row-major out
__global__ __launch_bounds__(256) void gemm_mfma_kernel(
    const short* __restrict__ A, const short* __restrict__ Bm,
    const float* __restrict__ bias, void* __restrict__ Cout,
    int M, int Nrows, int K, int Nout) {
  __shared__ short As[2][2048];  // 2 slabs x (4 kc x 64 rows x 8)
  __shared__ short Bs[2][4096];  // 2 slabs x (4 kc x 128 rows x 8)
  const int tid  = threadIdx.x;
  const int lane = tid & 63;
  const int w    = tid >> 6;
  const int bm = blockIdx.y * 64;
  const int bn = blockIdx.x * 128;
  const int wm = (w >> 1) * 32;
  const int wn = (w & 1) * 64;
  const int m_lane = lane & 15;
  const int quad   = lane >> 4;

  f32x4 acc[2][4];
#pragma unroll
  for (int i = 0; i < 2; ++i)
#pragma unroll
    for (int j = 0; j < 4; ++j) acc[i][j] = f32x4{0.f, 0.f, 0.f, 0.f};

  const size_t strideA = (size_t)M * 32;       // elements per 4-octet K-step
  const size_t strideB = (size_t)Nrows * 32;
  const short* pA  = A  + ((size_t)w * M + bm) * 8 + lane * 8;
  const short* pB0 = Bm + ((size_t)w * Nrows + bn) * 8 + lane * 8;
  const short* pB1 = pB0 + 64 * 8;
  const int lA  = w * 512;       // wave-uniform LDS bases (shorts)
  const int lB0 = w * 1024;
  const int lB1 = lB0 + 512;

  // prologue: stage slab 0 into buf 0
  load16_lds(pA,  &As[0][lA]);
  load16_lds(pB0, &Bs[0][lB0]);
  load16_lds(pB1, &Bs[0][lB1]);

  const int iters = K >> 5;
  for (int it = 0; it < iters; ++it) {
    const int cur = it & 1, nxt = cur ^ 1;
    __syncthreads();   // drains buf[cur] staging; guards buf[nxt] reuse
    if (it + 1 < iters) {
      pA += strideA; pB0 += strideB; pB1 += strideB;
      load16_lds(pA,  &As[nxt][lA]);
      load16_lds(pB0, &Bs[nxt][lB0]);
      load16_lds(pB1, &Bs[nxt][lB1]);
    }
    short8 af[2], bf[4];
#pragma unroll
    for (int i = 0; i < 2; ++i)
      af[i] = *(const short8*)&As[cur][quad * 512 + (wm + i * 16 + m_lane) * 8];
#pragma unroll
    for (int j = 0; j < 4; ++j)
      bf[j] = *(const short8*)&Bs[cur][quad * 1024 + (wn + j * 16 + m_lane) * 8];
#pragma unroll
    for (int i = 0; i < 2; ++i)
#pragma unroll
      for (int j = 0; j < 4; ++j)
        acc[i][j] = __builtin_amdgcn_mfma_f32_16x16x32_bf16(af[i], bf[j], acc[i][j], 0, 0, 0);
  }

  // epilogue: C/D layout col=lane&15, row=quad*4+reg
  const int row0 = bm + wm + quad * 4;
  const int col0 = bn + wn + m_lane;
  if (MODE == 0) {
    __hip_bfloat16* Cb = (__hip_bfloat16*)Cout;
#pragma unroll
    for (int j = 0; j < 4; ++j) {
      int col = col0 + j * 16;
      float bsv = bias[col];
      __hip_bfloat16* base = Cb + ((size_t)(col >> 3) * M) * 8 + (col & 7);
#pragma unroll
      for (int i = 0; i < 2; ++i)
#pragma unroll
        for (int r = 0; r < 4; ++r) {
          int row = row0 + i * 16 + r;
          float v = acc[i][j][r] + bsv;
          v = v > 0.f ? v : 0.f;
          base[(size_t)row * 8] = __float2bfloat16(v);
        }
    }
  } else {
    float* Cf = (float*)Cout;
#pragma unroll
    for (int j = 0; j < 4; ++j) {
      int col = col0 + j * 16;
      float bsv = bias[col];
#pragma unroll
      for (int i = 0; i < 2; ++i)
#pragma unroll
        for (int r = 0; r < 4; ++r) {
          int row = row0 + i * 16 + r;
          Cf[(size_t)row * Nout + col] = acc[i][j][r] + bsv;
        }
    }
  }
}

// ------- fused loss: softmax CE + accuracy + scalar MSE (col 1000) --------
__global__ __launch_bounds__(256) void loss_kernel(
    const float* __restrict__ logits, const int* __restrict__ target,
    const float* __restrict__ tgt_scal,
    float* __restrict__ pv, float* __restrict__ pa, float* __restrict__ ps) {
  int tid  = threadIdx.x;
  int lane = tid & 63;
  int w    = tid >> 6;
  int b    = blockIdx.x * 4 + w;
  const float*  row  = logits + (size_t)b * NPAD2;
  const float4* row4 = (const float4*)row;
  float v[16];
  float vmax = -INFINITY;
  int   imax = 0x7fffffff;
#pragma unroll
  for (int k = 0; k < 4; ++k) {
    int c4 = lane + 64 * k;
    float4 x = row4[c4];
    float e0 = x.x, e1 = x.y, e2 = x.z, e3 = x.w;
    int idx = c4 * 4;
    if (idx + 0 >= C_) e0 = -INFINITY;
    if (idx + 1 >= C_) e1 = -INFINITY;
    if (idx + 2 >= C_) e2 = -INFINITY;
    if (idx + 3 >= C_) e3 = -INFINITY;
    v[k * 4 + 0] = e0; v[k * 4 + 1] = e1; v[k * 4 + 2] = e2; v[k * 4 + 3] = e3;
    if (e0 > vmax) { vmax = e0; imax = idx + 0; }
    if (e1 > vmax) { vmax = e1; imax = idx + 1; }
    if (e2 > vmax) { vmax = e2; imax = idx + 2; }
    if (e3 > vmax) { vmax = e3; imax = idx + 3; }
  }
#pragma unroll
  for (int o = 32; o > 0; o >>= 1) {
    float ov = __shfl_down(vmax, o, 64);
    int   oi = __shfl_down(imax, o, 64);
    if (ov > vmax || (ov == vmax && oi < imax)) { vmax = ov; imax = oi; }
  }
  vmax = __shfl(vmax, 0, 64);
  float se = 0.f;
#pragma unroll
  for (int j = 0; j < 16; ++j) se += expf(v[j] - vmax);
#pragma unroll
  for (int o = 32; o > 0; o >>= 1) se += __shfl_down(se, o, 64);
  __shared__ float s_nll[4], s_acc[4], s_sq[4];
  if (lane == 0) {
    int t = target[b];
    float logp = row[t] - vmax - logf(se);
    s_nll[w] = -logp;
    s_acc[w] = (imax == t) ? 1.f : 0.f;
    float d = row[C_] - tgt_scal[b];     // fused scalar head output
    s_sq[w] = d * d;
  }
  __syncthreads();
  if (tid == 0) {
    pv[blockIdx.x] = s_nll[0] + s_nll[1] + s_nll[2] + s_nll[3];
    pa[blockIdx.x] = s_acc[0] + s_acc[1] + s_acc[2] + s_acc[3];
    ps[blockIdx.x] = s_sq[0] + s_sq[1] + s_sq[2] + s_sq[3];
  }
}

// ---------------- finalize: reduce partials ----------------
__global__ __launch_bounds__(256) void finalize_kernel(
    const float* __restrict__ pv, const float* __restrict__ pa,
    const float* __restrict__ ps, float* __restrict__ out) {
  int tid  = threadIdx.x;
  int lane = tid & 63;
  int w    = tid >> 6;
  float nll = 0.f, acc = 0.f, sq = 0.f;
  for (int i = tid; i < NPART; i += 256) {
    nll += pv[i]; acc += pa[i]; sq += ps[i];
  }
#pragma unroll
  for (int o = 32; o > 0; o >>= 1) {
    nll += __shfl_down(nll, o, 64);
    acc += __shfl_down(acc, o, 64);
    sq  += __shfl_down(sq,  o, 64);
  }
  __shared__ float sn[4], sa[4], ss[4];
  if (lane == 0) { sn[w] = nll; sa[w] = acc; ss[w] = sq; }
  __syncthreads();
  if (tid == 0) {
    float lv = (sn[0] + sn[1] + sn[2] + sn[3]) * (1.f / B_);
    float ls = (ss[0] + ss[1] + ss[2] + ss[3]) * (1.f / B_);
    float ac = (sa[0] + sa[1] + sa[2] + sa[3]) * (1.f / B_);
    out[0] = lv + ls;
    out[1] = lv;
    out[2] = ls;
    out[3] = ac;
  }
}

extern "C" void kernel_launch(void* const* d_in, const int* in_sizes, int n_in,
                              void* d_out, int out_size, void* d_ws, size_t ws_size,
                              hipStream_t stream) {
  const float* feature  = (const float*)d_in[0];
  const float* var_flat = (const float*)d_in[1];
  const int*   seg_ids  = (const int*)d_in[2];
  const int*   tgt_vec  = (const int*)d_in[3];
  const float* tgt_scal = (const float*)d_in[4];
  const float* Wv = (const float*)d_in[5];
  const float* bv = (const float*)d_in[6];
  const float* W1 = (const float*)d_in[7];
  const float* b1 = (const float*)d_in[8];
  const float* W2 = (const float*)d_in[9];
  const float* b2 = (const float*)d_in[10];
  const float* Ws = (const float*)d_in[11];
  const float* bs = (const float*)d_in[12];
  float* out = (float*)d_out;

  char* ws = (char*)d_ws;
  float* means  = (float*)(ws + WS_MEANS);
  float* pv     = (float*)(ws + WS_PV);
  float* pa     = (float*)(ws + WS_PA);
  float* ps     = (float*)(ws + WS_PS);
  float* b2p    = (float*)(ws + WS_B2P);
  int*   starts = (int*)(ws + WS_STARTS);
  __hip_bfloat16* comb_oct = (__hip_bfloat16*)(ws + WS_COMBINED);
  __hip_bfloat16* W1oct    = (__hip_bfloat16*)(ws + WS_W1BF);
  __hip_bfloat16* W2oct    = (__hip_bfloat16*)(ws + WS_W2BF);
  __hip_bfloat16* hid_oct  = (__hip_bfloat16*)(ws + WS_HIDDEN);
  float*          logits   = (float*)(ws + WS_LOGITS);

  // 1) segment boundaries (one streaming scan; kills prep's binary search)
  bounds_kernel<<<(T_ + 255) / 256, 256, 0, stream>>>(seg_ids, starts);

  // 2) merged prep: weight converts + bias pad + segment means (1 dispatch)
  prep_kernel<<<PREP_BLOCKS, 256, 0, stream>>>(
      var_flat, starts, means, W1, W1oct, W2, Ws, W2oct, b2, bs, b2p);

  // 3) combined = feature + means @ Wv^T + bv  (octet-major bf16)
  {
    dim3 grid(D_ / 64, B_ / 32);
    combined_kernel<<<grid, 256, 0, stream>>>(feature, means, Wv, bv, comb_oct);
  }

  // 4) hidden = relu(combined @ W1^T + b1), octet-major out
  {
    dim3 grid(H_ / 128, B_ / 64);     // 16 x 64 = 1024 blocks
    gemm_mfma_kernel<0><<<grid, 256, 0, stream>>>(
        (const short*)comb_oct, (const short*)W1oct, b1, hid_oct, B_, H_, D_, H_);
  }

  // 5) logits[4096 x 1024] = hidden @ W2p^T + b2p (col 1000 = scalar head)
  {
    dim3 grid(NPAD2 / 128, B_ / 64);  // 8 x 64 = 512 blocks
    gemm_mfma_kernel<1><<<grid, 256, 0, stream>>>(
        (const short*)hid_oct, (const short*)W2oct, b2p, logits, B_, NPAD2, H_, NPAD2);
  }

  // 6) fused CE + accuracy + scalar MSE (partials)
  loss_kernel<<<B_ / 4, 256, 0, stream>>>(logits, tgt_vec, tgt_scal, pv, pa, ps);

  // 7) finalize
  finalize_kernel<<<1, 256, 0, stream>>>(pv, pa, ps, out);
}